// Round 1
// baseline (514.626 us; speedup 1.0000x reference)
//
#include <hip/hip_runtime.h>
#include <hip/hip_bf16.h>

#define DD 512
#define MM 64
#define HH 8
#define HDIM 64

typedef __bf16 bf16x8 __attribute__((ext_vector_type(8)));
typedef float f32x4 __attribute__((ext_vector_type(4)));

static __device__ __forceinline__ unsigned short bfbits(float f) {
    union { float f; unsigned u; } x; x.f = f;
    unsigned r = x.u + 0x7fffu + ((x.u >> 16) & 1u);
    return (unsigned short)(r >> 16);
}
static __device__ __forceinline__ __bf16 to_bf16(float f) {
    union { unsigned short s; __bf16 b; } y; y.s = bfbits(f); return y.b;
}

// ---------------- prep 1: k/v projections of memory (tiny) ----------------
__global__ void prep_kv(const float* __restrict__ memory,
                        const float* __restrict__ Wk, const float* __restrict__ bk,
                        const float* __restrict__ Wv, const float* __restrict__ bv,
                        float* __restrict__ kproj, float* __restrict__ vproj) {
    __shared__ float mrow[DD];
    const int m = blockIdx.x;
    const int t = threadIdx.x;
    for (int i = t; i < DD; i += 256) mrow[i] = memory[(size_t)m * DD + i];
    __syncthreads();
    for (int jj = 0; jj < 2; ++jj) {
        const int j = t + jj * 256;
        const float* wkr = Wk + (size_t)j * DD;
        const float* wvr = Wv + (size_t)j * DD;
        float sk = 0.f, sv = 0.f;
        for (int d = 0; d < DD; ++d) {
            const float md = mrow[d];
            sk += md * wkr[d];
            sv += md * wvr[d];
        }
        kproj[(size_t)m * DD + j] = sk + bk[j];
        vproj[(size_t)m * DD + j] = sv + bv[j];
    }
}

// ---------------- prep 2: fold projections into W2t / b2 / W3t ----------------
// c = h*64 + m.
// W2t[c][d] = sum_hd Wq[h*64+hd, d] * kproj[m, h*64+hd]   (bf16, [512][512])
// b2[c]     = sum_hd bq[h*64+hd]    * kproj[m, h*64+hd]   (f32)
// W3t[j][c] = sum_hd vproj[m, h*64+hd] * Wo[j, h*64+hd]   (bf16, [512][512])
__global__ void prep_w(const float* __restrict__ Wq, const float* __restrict__ bq,
                       const float* __restrict__ Wo,
                       const float* __restrict__ kproj, const float* __restrict__ vproj,
                       __bf16* __restrict__ W2t, float* __restrict__ b2,
                       __bf16* __restrict__ W3t) {
    const int i = blockIdx.x;   // c for W2t/b2, j for W3t
    const int t = threadIdx.x;
    __shared__ float kp[HDIM];
    __shared__ float worow[DD];
    const int m = i & 63, h = i >> 6;
    if (t < HDIM) kp[t] = kproj[(size_t)m * DD + h * HDIM + t];
    for (int d = t; d < DD; d += 256) worow[d] = Wo[(size_t)i * DD + d];
    __syncthreads();
    for (int dd2 = 0; dd2 < 2; ++dd2) {
        const int d = t + dd2 * 256;
        float s = 0.f;
        #pragma unroll 8
        for (int hd = 0; hd < HDIM; ++hd)
            s += Wq[(size_t)(h * HDIM + hd) * DD + d] * kp[hd];
        W2t[(size_t)i * DD + d] = to_bf16(s);
    }
    if (t == 0) {
        float s = 0.f;
        for (int hd = 0; hd < HDIM; ++hd) s += bq[h * HDIM + hd] * kp[hd];
        b2[i] = s;
    }
    for (int cc = 0; cc < 2; ++cc) {
        const int c = t + cc * 256;
        const int mc = c & 63, hc = c >> 6;
        float s = 0.f;
        #pragma unroll 8
        for (int hd = 0; hd < HDIM; ++hd)
            s += vproj[(size_t)mc * DD + hc * HDIM + hd] * worow[hc * HDIM + hd];
        W3t[(size_t)i * DD + c] = to_bf16(s);
    }
}

// ---------------- main fused kernel ----------------
// Per block: 64 rows. 4 waves; wave w owns output cols [w*128, w*128+128)
// (= heads 2w, 2w+1 for the score matrix -> softmax is wave-local).
__global__ __launch_bounds__(256) void attn_main(
    const float* __restrict__ x, const int* __restrict__ mask,
    const __bf16* __restrict__ W2t, const float* __restrict__ b2,
    const __bf16* __restrict__ W3t, const float* __restrict__ bo,
    float* __restrict__ out) {
    __shared__ short lds_s[64 * 512];   // 64 KiB, bf16 tile (x, then attn)

    const int tid = threadIdx.x;
    const int lane = tid & 63;
    const int w = tid >> 6;
    const int wcol = w * 128;
    const int lc = lane & 15;
    const int grp = lane >> 4;
    const int lk = grp * 8;
    const int r0 = blockIdx.x * 64;

    // ---- stage x (fp32 -> bf16, XOR-swizzled rows to kill ds_read_b128 conflicts)
    {
        const float4* xv = (const float4*)(x + (size_t)r0 * DD);
        #pragma unroll
        for (int it = 0; it < 32; ++it) {
            const int idx4 = it * 256 + tid;
            const int row = idx4 >> 7;      // 128 float4 per row
            const int c4 = idx4 & 127;
            const float4 v = xv[(size_t)row * 128 + c4];
            uint2 u;
            u.x = (unsigned)bfbits(v.x) | ((unsigned)bfbits(v.y) << 16);
            u.y = (unsigned)bfbits(v.z) | ((unsigned)bfbits(v.w) << 16);
            const int off = row * 1024 + ((c4 * 8) ^ ((row & 7) << 4));
            *(uint2*)((char*)lds_s + off) = u;
        }
    }
    __syncthreads();

    float b2v[8], bov[8];
    #pragma unroll
    for (int ct = 0; ct < 8; ++ct) {
        b2v[ct] = b2[wcol + ct * 16 + lc];
        bov[ct] = bo[wcol + ct * 16 + lc];
    }

    // ---- GEMM1: S = x @ W2 (K=512)
    f32x4 acc[4][8];
    #pragma unroll
    for (int rt = 0; rt < 4; ++rt)
        #pragma unroll
        for (int ct = 0; ct < 8; ++ct)
            acc[rt][ct] = (f32x4){0.f, 0.f, 0.f, 0.f};

    #pragma unroll 2
    for (int kt = 0; kt < 16; ++kt) {
        const int k0 = kt * 32;
        bf16x8 bfr[8];
        #pragma unroll
        for (int ct = 0; ct < 8; ++ct)
            bfr[ct] = *(const bf16x8*)(W2t + ((size_t)(wcol + ct * 16 + lc) * DD + k0 + lk));
        bf16x8 afr[4];
        #pragma unroll
        for (int rt = 0; rt < 4; ++rt) {
            const int row = rt * 16 + lc;
            const int off = row * 1024 + (((k0 + lk) * 2) ^ ((row & 7) << 4));
            afr[rt] = *(const bf16x8*)((const char*)lds_s + off);
        }
        #pragma unroll
        for (int rt = 0; rt < 4; ++rt)
            #pragma unroll
            for (int ct = 0; ct < 8; ++ct)
                acc[rt][ct] = __builtin_amdgcn_mfma_f32_16x16x32_bf16(afr[rt], bfr[ct], acc[rt][ct], 0, 0, 0);
    }
    __syncthreads();   // everyone done reading x from LDS

    // ---- softmax per head (64-col chunks), write attn (bf16) back to LDS
    #pragma unroll
    for (int rt = 0; rt < 4; ++rt) {
        const int rloc0 = rt * 16 + grp * 4;
        const int4 mv = *(const int4*)(mask + r0 + rloc0);
        const int mk[4] = {mv.x, mv.y, mv.z, mv.w};
        #pragma unroll
        for (int hl = 0; hl < 2; ++hl) {
            #pragma unroll
            for (int j = 0; j < 4; ++j) {
                float s0 = (acc[rt][hl * 4 + 0][j] + b2v[hl * 4 + 0]) * 0.125f;
                float s1 = (acc[rt][hl * 4 + 1][j] + b2v[hl * 4 + 1]) * 0.125f;
                float s2 = (acc[rt][hl * 4 + 2][j] + b2v[hl * 4 + 2]) * 0.125f;
                float s3 = (acc[rt][hl * 4 + 3][j] + b2v[hl * 4 + 3]) * 0.125f;
                float mx = fmaxf(fmaxf(s0, s1), fmaxf(s2, s3));
                mx = fmaxf(mx, __shfl_xor(mx, 1));
                mx = fmaxf(mx, __shfl_xor(mx, 2));
                mx = fmaxf(mx, __shfl_xor(mx, 4));
                mx = fmaxf(mx, __shfl_xor(mx, 8));
                float p0 = __expf(s0 - mx);
                float p1 = __expf(s1 - mx);
                float p2 = __expf(s2 - mx);
                float p3 = __expf(s3 - mx);
                float sm = (p0 + p1) + (p2 + p3);
                sm += __shfl_xor(sm, 1);
                sm += __shfl_xor(sm, 2);
                sm += __shfl_xor(sm, 4);
                sm += __shfl_xor(sm, 8);
                float a0, a1, a2, a3;
                if (mk[j] == 0) {
                    a0 = a1 = a2 = a3 = 0.015625f;   // fp32 -1e9 bias rounds to uniform attn
                } else {
                    const float inv = 1.0f / sm;
                    a0 = p0 * inv; a1 = p1 * inv; a2 = p2 * inv; a3 = p3 * inv;
                }
                const int row = rloc0 + j;
                const int base = row * 1024;
                const int sw = (row & 7) << 4;
                *(short*)((char*)lds_s + base + (((wcol + (hl * 4 + 0) * 16 + lc) * 2) ^ sw)) = (short)bfbits(a0);
                *(short*)((char*)lds_s + base + (((wcol + (hl * 4 + 1) * 16 + lc) * 2) ^ sw)) = (short)bfbits(a1);
                *(short*)((char*)lds_s + base + (((wcol + (hl * 4 + 2) * 16 + lc) * 2) ^ sw)) = (short)bfbits(a2);
                *(short*)((char*)lds_s + base + (((wcol + (hl * 4 + 3) * 16 + lc) * 2) ^ sw)) = (short)bfbits(a3);
            }
        }
    }
    __syncthreads();   // attn tile complete in LDS

    // ---- GEMM2: out = attn @ W3 (K=512) + bo
    f32x4 acc2[4][8];
    #pragma unroll
    for (int rt = 0; rt < 4; ++rt)
        #pragma unroll
        for (int ct = 0; ct < 8; ++ct)
            acc2[rt][ct] = (f32x4){0.f, 0.f, 0.f, 0.f};

    #pragma unroll 2
    for (int kt = 0; kt < 16; ++kt) {
        const int k0 = kt * 32;
        bf16x8 bfr[8];
        #pragma unroll
        for (int ct = 0; ct < 8; ++ct)
            bfr[ct] = *(const bf16x8*)(W3t + ((size_t)(wcol + ct * 16 + lc) * DD + k0 + lk));
        bf16x8 afr[4];
        #pragma unroll
        for (int rt = 0; rt < 4; ++rt) {
            const int row = rt * 16 + lc;
            const int off = row * 1024 + (((k0 + lk) * 2) ^ ((row & 7) << 4));
            afr[rt] = *(const bf16x8*)((const char*)lds_s + off);
        }
        #pragma unroll
        for (int rt = 0; rt < 4; ++rt)
            #pragma unroll
            for (int ct = 0; ct < 8; ++ct)
                acc2[rt][ct] = __builtin_amdgcn_mfma_f32_16x16x32_bf16(afr[rt], bfr[ct], acc2[rt][ct], 0, 0, 0);
    }

    // ---- epilogue: + bo, fp32 store
    #pragma unroll
    for (int rt = 0; rt < 4; ++rt) {
        const int gr = r0 + rt * 16 + grp * 4;
        #pragma unroll
        for (int ct = 0; ct < 8; ++ct) {
            const int jc = wcol + ct * 16 + lc;
            #pragma unroll
            for (int j = 0; j < 4; ++j)
                out[(size_t)(gr + j) * DD + jc] = acc2[rt][ct][j] + bov[ct];
        }
    }
}

extern "C" void kernel_launch(void* const* d_in, const int* in_sizes, int n_in,
                              void* d_out, int out_size, void* d_ws, size_t ws_size,
                              hipStream_t stream) {
    const float* qf     = (const float*)d_in[0];
    const int*   mask   = (const int*)d_in[1];
    const float* memory = (const float*)d_in[2];
    const float* Wq     = (const float*)d_in[3];
    const float* bq     = (const float*)d_in[4];
    const float* Wk     = (const float*)d_in[5];
    const float* bk     = (const float*)d_in[6];
    const float* Wv     = (const float*)d_in[7];
    const float* bv     = (const float*)d_in[8];
    const float* Wo     = (const float*)d_in[9];
    const float* bo     = (const float*)d_in[10];

    char* ws = (char*)d_ws;
    float*  kproj = (float*)ws;                  // 128 KB
    float*  vproj = (float*)(ws + 131072);       // 128 KB
    float*  b2    = (float*)(ws + 262144);       // 2 KB
    __bf16* W2t   = (__bf16*)(ws + 264192);      // 512 KB
    __bf16* W3t   = (__bf16*)(ws + 788480);      // 512 KB

    prep_kv<<<64, 256, 0, stream>>>(memory, Wk, bk, Wv, bv, kproj, vproj);
    prep_w<<<512, 256, 0, stream>>>(Wq, bq, Wo, kproj, vproj, W2t, b2, W3t);
    attn_main<<<2048, 256, 0, stream>>>(qf, mask, W2t, b2, W3t, bo, (float*)d_out);
}

// Round 2
// 415.963 us; speedup vs baseline: 1.2372x; 1.2372x over previous
//
#include <hip/hip_runtime.h>
#include <hip/hip_bf16.h>

#define DD 512
#define MM 64
#define HH 8
#define HDIM 64

typedef __bf16 bf16x8 __attribute__((ext_vector_type(8)));
typedef float f32x4 __attribute__((ext_vector_type(4)));

static __device__ __forceinline__ unsigned short bfbits(float f) {
    union { float f; unsigned u; } x; x.f = f;
    unsigned r = x.u + 0x7fffu + ((x.u >> 16) & 1u);
    return (unsigned short)(r >> 16);
}
static __device__ __forceinline__ __bf16 to_bf16(float f) {
    union { unsigned short s; __bf16 b; } y; y.s = bfbits(f); return y.b;
}

// ---------------- prep 1: k/v projections of memory (tiny) ----------------
__global__ void prep_kv(const float* __restrict__ memory,
                        const float* __restrict__ Wk, const float* __restrict__ bk,
                        const float* __restrict__ Wv, const float* __restrict__ bv,
                        float* __restrict__ kproj, float* __restrict__ vproj) {
    __shared__ float mrow[DD];
    const int m = blockIdx.x;
    const int t = threadIdx.x;
    for (int i = t; i < DD; i += 256) mrow[i] = memory[(size_t)m * DD + i];
    __syncthreads();
    for (int jj = 0; jj < 2; ++jj) {
        const int j = t + jj * 256;
        const float* wkr = Wk + (size_t)j * DD;
        const float* wvr = Wv + (size_t)j * DD;
        float sk = 0.f, sv = 0.f;
        for (int d = 0; d < DD; ++d) {
            const float md = mrow[d];
            sk += md * wkr[d];
            sv += md * wvr[d];
        }
        kproj[(size_t)m * DD + j] = sk + bk[j];
        vproj[(size_t)m * DD + j] = sv + bv[j];
    }
}

// ---------------- prep 2: fold projections into W2t / b2 / W3t ----------------
// c = h*64 + m.
// W2t[c][d] = sum_hd Wq[h*64+hd, d] * kproj[m, h*64+hd]   (bf16, [512][512])
// b2[c]     = sum_hd bq[h*64+hd]    * kproj[m, h*64+hd]   (f32)
// W3t[j][c] = sum_hd vproj[m, h*64+hd] * Wo[j, h*64+hd]   (bf16, [512][512])
__global__ void prep_w(const float* __restrict__ Wq, const float* __restrict__ bq,
                       const float* __restrict__ Wo,
                       const float* __restrict__ kproj, const float* __restrict__ vproj,
                       __bf16* __restrict__ W2t, float* __restrict__ b2,
                       __bf16* __restrict__ W3t) {
    const int i = blockIdx.x;   // c for W2t/b2, j for W3t
    const int t = threadIdx.x;
    __shared__ float kp[HDIM];
    __shared__ float worow[DD];
    const int m = i & 63, h = i >> 6;
    if (t < HDIM) kp[t] = kproj[(size_t)m * DD + h * HDIM + t];
    for (int d = t; d < DD; d += 256) worow[d] = Wo[(size_t)i * DD + d];
    __syncthreads();
    for (int dd2 = 0; dd2 < 2; ++dd2) {
        const int d = t + dd2 * 256;
        float s = 0.f;
        #pragma unroll 8
        for (int hd = 0; hd < HDIM; ++hd)
            s += Wq[(size_t)(h * HDIM + hd) * DD + d] * kp[hd];
        W2t[(size_t)i * DD + d] = to_bf16(s);
    }
    if (t == 0) {
        float s = 0.f;
        for (int hd = 0; hd < HDIM; ++hd) s += bq[h * HDIM + hd] * kp[hd];
        b2[i] = s;
    }
    for (int cc = 0; cc < 2; ++cc) {
        const int c = t + cc * 256;
        const int mc = c & 63, hc = c >> 6;
        float s = 0.f;
        #pragma unroll 8
        for (int hd = 0; hd < HDIM; ++hd)
            s += vproj[(size_t)mc * DD + hc * HDIM + hd] * worow[hc * HDIM + hd];
        W3t[(size_t)i * DD + c] = to_bf16(s);
    }
}

// ---------------- main fused kernel ----------------
// Per block: 64 rows. 4 waves; wave w owns output cols [w*128, w*128+128)
// (= heads 2w, 2w+1 for the score matrix -> softmax is wave-local).
// Software-pipelined K-loops: double-buffered A/B fragment registers,
// B(kt=0) hoisted under staging (GEMM1) / softmax (GEMM2), setprio on MFMA.
__global__ __launch_bounds__(256, 2) void attn_main(
    const float* __restrict__ x, const int* __restrict__ mask,
    const __bf16* __restrict__ W2t, const float* __restrict__ b2,
    const __bf16* __restrict__ W3t, const float* __restrict__ bo,
    float* __restrict__ out) {
    __shared__ short lds_s[64 * 512];   // 64 KiB, bf16 tile (x, then attn)

    const int tid = threadIdx.x;
    const int lane = tid & 63;
    const int w = tid >> 6;
    const int wcol = w * 128;
    const int lc = lane & 15;
    const int grp = lane >> 4;
    const int lk = grp * 8;
    const int r0 = blockIdx.x * 64;

    // per-wave B base: col = wcol + ct*16 + lc, k-slice lk..lk+7
    const __bf16* Bb1 = W2t + (size_t)(wcol + lc) * DD + lk;
    const __bf16* Bb2 = W3t + (size_t)(wcol + lc) * DD + lk;

    // ---- hoist GEMM1 kt=0 B-fragments (independent of LDS staging)
    bf16x8 bb[2][8];
    #pragma unroll
    for (int ct = 0; ct < 8; ++ct)
        bb[0][ct] = *(const bf16x8*)(Bb1 + (size_t)ct * 16 * DD);

    // ---- stage x (fp32 -> bf16, XOR-swizzled rows to kill ds_read_b128 conflicts)
    {
        const float4* xv = (const float4*)(x + (size_t)r0 * DD);
        #pragma unroll
        for (int it = 0; it < 32; ++it) {
            const int idx4 = it * 256 + tid;
            const int row = idx4 >> 7;      // 128 float4 per row
            const int c4 = idx4 & 127;
            const float4 v = xv[(size_t)row * 128 + c4];
            uint2 u;
            u.x = (unsigned)bfbits(v.x) | ((unsigned)bfbits(v.y) << 16);
            u.y = (unsigned)bfbits(v.z) | ((unsigned)bfbits(v.w) << 16);
            const int off = row * 1024 + ((c4 * 8) ^ ((row & 7) << 4));
            *(uint2*)((char*)lds_s + off) = u;
        }
    }
    __syncthreads();

    float b2v[8], bov[8];
    #pragma unroll
    for (int ct = 0; ct < 8; ++ct) {
        b2v[ct] = b2[wcol + ct * 16 + lc];
        bov[ct] = bo[wcol + ct * 16 + lc];
    }

    // A-fragment LDS read (swizzled). row fixed per rt; k0 varies.
    #define LDA(rt, k0) \
        (*(const bf16x8*)((const char*)lds_s + \
            ((rt) * 16 + lc) * 1024 + ((((k0) + lk) * 2) ^ ((((rt) * 16 + lc) & 7) << 4))))

    // ---- GEMM1: S = x @ W2 (K=512), pipelined
    f32x4 acc[4][8];
    #pragma unroll
    for (int rt = 0; rt < 4; ++rt)
        #pragma unroll
        for (int ct = 0; ct < 8; ++ct)
            acc[rt][ct] = (f32x4){0.f, 0.f, 0.f, 0.f};

    bf16x8 aa[2][4];
    #pragma unroll
    for (int rt = 0; rt < 4; ++rt) aa[0][rt] = LDA(rt, 0);

    #pragma unroll
    for (int kt = 0; kt < 16; ++kt) {
        const int cur = kt & 1, nxt = cur ^ 1;
        if (kt < 15) {
            const int k0n = (kt + 1) * 32;
            #pragma unroll
            for (int ct = 0; ct < 8; ++ct)
                bb[nxt][ct] = *(const bf16x8*)(Bb1 + (size_t)ct * 16 * DD + k0n);
            #pragma unroll
            for (int rt = 0; rt < 4; ++rt) aa[nxt][rt] = LDA(rt, k0n);
        }
        __builtin_amdgcn_s_setprio(1);
        #pragma unroll
        for (int rt = 0; rt < 4; ++rt)
            #pragma unroll
            for (int ct = 0; ct < 8; ++ct)
                acc[rt][ct] = __builtin_amdgcn_mfma_f32_16x16x32_bf16(aa[cur][rt], bb[cur][ct], acc[rt][ct], 0, 0, 0);
        __builtin_amdgcn_s_setprio(0);
    }

    // ---- hoist GEMM2 kt=0 B-fragments (hide their latency under softmax)
    bf16x8 bb2[2][8];
    #pragma unroll
    for (int ct = 0; ct < 8; ++ct)
        bb2[0][ct] = *(const bf16x8*)(Bb2 + (size_t)ct * 16 * DD);

    __syncthreads();   // everyone done reading x from LDS

    // ---- softmax per head (64-col chunks), write attn (bf16) back to LDS
    #pragma unroll
    for (int rt = 0; rt < 4; ++rt) {
        const int rloc0 = rt * 16 + grp * 4;
        const int4 mv = *(const int4*)(mask + r0 + rloc0);
        const int mk[4] = {mv.x, mv.y, mv.z, mv.w};
        #pragma unroll
        for (int hl = 0; hl < 2; ++hl) {
            #pragma unroll
            for (int j = 0; j < 4; ++j) {
                float s0 = (acc[rt][hl * 4 + 0][j] + b2v[hl * 4 + 0]) * 0.125f;
                float s1 = (acc[rt][hl * 4 + 1][j] + b2v[hl * 4 + 1]) * 0.125f;
                float s2 = (acc[rt][hl * 4 + 2][j] + b2v[hl * 4 + 2]) * 0.125f;
                float s3 = (acc[rt][hl * 4 + 3][j] + b2v[hl * 4 + 3]) * 0.125f;
                float mx = fmaxf(fmaxf(s0, s1), fmaxf(s2, s3));
                mx = fmaxf(mx, __shfl_xor(mx, 1));
                mx = fmaxf(mx, __shfl_xor(mx, 2));
                mx = fmaxf(mx, __shfl_xor(mx, 4));
                mx = fmaxf(mx, __shfl_xor(mx, 8));
                float p0 = __expf(s0 - mx);
                float p1 = __expf(s1 - mx);
                float p2 = __expf(s2 - mx);
                float p3 = __expf(s3 - mx);
                float sm = (p0 + p1) + (p2 + p3);
                sm += __shfl_xor(sm, 1);
                sm += __shfl_xor(sm, 2);
                sm += __shfl_xor(sm, 4);
                sm += __shfl_xor(sm, 8);
                float a0, a1, a2, a3;
                if (mk[j] == 0) {
                    a0 = a1 = a2 = a3 = 0.015625f;   // fp32 -1e9 bias rounds to uniform attn
                } else {
                    const float inv = 1.0f / sm;
                    a0 = p0 * inv; a1 = p1 * inv; a2 = p2 * inv; a3 = p3 * inv;
                }
                const int row = rloc0 + j;
                const int base = row * 1024;
                const int sw = (row & 7) << 4;
                *(short*)((char*)lds_s + base + (((wcol + (hl * 4 + 0) * 16 + lc) * 2) ^ sw)) = (short)bfbits(a0);
                *(short*)((char*)lds_s + base + (((wcol + (hl * 4 + 1) * 16 + lc) * 2) ^ sw)) = (short)bfbits(a1);
                *(short*)((char*)lds_s + base + (((wcol + (hl * 4 + 2) * 16 + lc) * 2) ^ sw)) = (short)bfbits(a2);
                *(short*)((char*)lds_s + base + (((wcol + (hl * 4 + 3) * 16 + lc) * 2) ^ sw)) = (short)bfbits(a3);
            }
        }
    }
    __syncthreads();   // attn tile complete in LDS

    // ---- GEMM2: out = attn @ W3 (K=512) + bo, pipelined
    f32x4 acc2[4][8];
    #pragma unroll
    for (int rt = 0; rt < 4; ++rt)
        #pragma unroll
        for (int ct = 0; ct < 8; ++ct)
            acc2[rt][ct] = (f32x4){0.f, 0.f, 0.f, 0.f};

    bf16x8 aa2[2][4];
    #pragma unroll
    for (int rt = 0; rt < 4; ++rt) aa2[0][rt] = LDA(rt, 0);

    #pragma unroll
    for (int kt = 0; kt < 16; ++kt) {
        const int cur = kt & 1, nxt = cur ^ 1;
        if (kt < 15) {
            const int k0n = (kt + 1) * 32;
            #pragma unroll
            for (int ct = 0; ct < 8; ++ct)
                bb2[nxt][ct] = *(const bf16x8*)(Bb2 + (size_t)ct * 16 * DD + k0n);
            #pragma unroll
            for (int rt = 0; rt < 4; ++rt) aa2[nxt][rt] = LDA(rt, k0n);
        }
        __builtin_amdgcn_s_setprio(1);
        #pragma unroll
        for (int rt = 0; rt < 4; ++rt)
            #pragma unroll
            for (int ct = 0; ct < 8; ++ct)
                acc2[rt][ct] = __builtin_amdgcn_mfma_f32_16x16x32_bf16(aa2[cur][rt], bb2[cur][ct], acc2[rt][ct], 0, 0, 0);
        __builtin_amdgcn_s_setprio(0);
    }
    #undef LDA

    // ---- epilogue: + bo, fp32 store
    #pragma unroll
    for (int rt = 0; rt < 4; ++rt) {
        const int gr = r0 + rt * 16 + grp * 4;
        #pragma unroll
        for (int ct = 0; ct < 8; ++ct) {
            const int jc = wcol + ct * 16 + lc;
            #pragma unroll
            for (int j = 0; j < 4; ++j)
                out[(size_t)(gr + j) * DD + jc] = acc2[rt][ct][j] + bov[ct];
        }
    }
}

extern "C" void kernel_launch(void* const* d_in, const int* in_sizes, int n_in,
                              void* d_out, int out_size, void* d_ws, size_t ws_size,
                              hipStream_t stream) {
    const float* qf     = (const float*)d_in[0];
    const int*   mask   = (const int*)d_in[1];
    const float* memory = (const float*)d_in[2];
    const float* Wq     = (const float*)d_in[3];
    const float* bq     = (const float*)d_in[4];
    const float* Wk     = (const float*)d_in[5];
    const float* bk     = (const float*)d_in[6];
    const float* Wv     = (const float*)d_in[7];
    const float* bv     = (const float*)d_in[8];
    const float* Wo     = (const float*)d_in[9];
    const float* bo     = (const float*)d_in[10];

    char* ws = (char*)d_ws;
    float*  kproj = (float*)ws;                  // 128 KB
    float*  vproj = (float*)(ws + 131072);       // 128 KB
    float*  b2    = (float*)(ws + 262144);       // 2 KB
    __bf16* W2t   = (__bf16*)(ws + 264192);      // 512 KB
    __bf16* W3t   = (__bf16*)(ws + 788480);      // 512 KB

    prep_kv<<<64, 256, 0, stream>>>(memory, Wk, bk, Wv, bv, kproj, vproj);
    prep_w<<<512, 256, 0, stream>>>(Wq, bq, Wo, kproj, vproj, W2t, b2, W3t);
    attn_main<<<2048, 256, 0, stream>>>(qf, mask, W2t, b2, W3t, bo, (float*)d_out);
}

// Round 4
// 398.134 us; speedup vs baseline: 1.2926x; 1.0448x over previous
//
#include <hip/hip_runtime.h>
#include <hip/hip_bf16.h>

#define DD 512
#define MM 64
#define HH 8
#define HDIM 64

typedef __bf16 bf16x8 __attribute__((ext_vector_type(8)));
typedef float f32x4 __attribute__((ext_vector_type(4)));

static __device__ __forceinline__ unsigned short bfbits(float f) {
    union { float f; unsigned u; } x; x.f = f;
    unsigned r = x.u + 0x7fffu + ((x.u >> 16) & 1u);
    return (unsigned short)(r >> 16);
}
static __device__ __forceinline__ __bf16 to_bf16(float f) {
    union { unsigned short s; __bf16 b; } y; y.s = bfbits(f); return y.b;
}

// ---------------- prep 1: k/v projections of memory (tiny) ----------------
__global__ void prep_kv(const float* __restrict__ memory,
                        const float* __restrict__ Wk, const float* __restrict__ bk,
                        const float* __restrict__ Wv, const float* __restrict__ bv,
                        float* __restrict__ kproj, float* __restrict__ vproj) {
    __shared__ float mrow[DD];
    const int m = blockIdx.x;
    const int t = threadIdx.x;
    for (int i = t; i < DD; i += 256) mrow[i] = memory[(size_t)m * DD + i];
    __syncthreads();
    for (int jj = 0; jj < 2; ++jj) {
        const int j = t + jj * 256;
        const float* wkr = Wk + (size_t)j * DD;
        const float* wvr = Wv + (size_t)j * DD;
        float sk = 0.f, sv = 0.f;
        for (int d = 0; d < DD; ++d) {
            const float md = mrow[d];
            sk += md * wkr[d];
            sv += md * wvr[d];
        }
        kproj[(size_t)m * DD + j] = sk + bk[j];
        vproj[(size_t)m * DD + j] = sv + bv[j];
    }
}

// ---------------- prep 2: fold projections into W2t / b2 / W3t ----------------
// c = h*64 + m.
// W2t[c][d] = sum_hd Wq[h*64+hd, d] * kproj[m, h*64+hd]   (bf16, [512][512])
// b2[c]     = sum_hd bq[h*64+hd]    * kproj[m, h*64+hd]   (f32)
// W3t[j][c] = sum_hd vproj[m, h*64+hd] * Wo[j, h*64+hd]   (bf16, [512][512])
__global__ void prep_w(const float* __restrict__ Wq, const float* __restrict__ bq,
                       const float* __restrict__ Wo,
                       const float* __restrict__ kproj, const float* __restrict__ vproj,
                       __bf16* __restrict__ W2t, float* __restrict__ b2,
                       __bf16* __restrict__ W3t) {
    const int i = blockIdx.x;   // c for W2t/b2, j for W3t
    const int t = threadIdx.x;
    __shared__ float kp[HDIM];
    __shared__ float worow[DD];
    const int m = i & 63, h = i >> 6;
    if (t < HDIM) kp[t] = kproj[(size_t)m * DD + h * HDIM + t];
    for (int d = t; d < DD; d += 256) worow[d] = Wo[(size_t)i * DD + d];
    __syncthreads();
    for (int dd2 = 0; dd2 < 2; ++dd2) {
        const int d = t + dd2 * 256;
        float s = 0.f;
        #pragma unroll 8
        for (int hd = 0; hd < HDIM; ++hd)
            s += Wq[(size_t)(h * HDIM + hd) * DD + d] * kp[hd];
        W2t[(size_t)i * DD + d] = to_bf16(s);
    }
    if (t == 0) {
        float s = 0.f;
        for (int hd = 0; hd < HDIM; ++hd) s += bq[h * HDIM + hd] * kp[hd];
        b2[i] = s;
    }
    for (int cc = 0; cc < 2; ++cc) {
        const int c = t + cc * 256;
        const int mc = c & 63, hc = c >> 6;
        float s = 0.f;
        #pragma unroll 8
        for (int hd = 0; hd < HDIM; ++hd)
            s += vproj[(size_t)mc * DD + hc * HDIM + hd] * worow[hc * HDIM + hd];
        W3t[(size_t)i * DD + c] = to_bf16(s);
    }
}

// ---------------- main fused kernel ----------------
// Per block: 64 rows. 4 waves; wave w owns output cols [w*128, w*128+128)
// (= heads 2w, 2w+1 for the score matrix -> softmax is wave-local).
// x loads and out stores are NON-TEMPORAL so the streams don't evict
// W2t/W3t (1 MB) from each XCD's L2 -> B-fragment reads stay L2-hits.
__global__ __launch_bounds__(256, 2) void attn_main(
    const float* __restrict__ x, const int* __restrict__ mask,
    const __bf16* __restrict__ W2t, const float* __restrict__ b2,
    const __bf16* __restrict__ W3t, const float* __restrict__ bo,
    float* __restrict__ out) {
    __shared__ short lds_s[64 * 512];   // 64 KiB, bf16 tile (x, then attn)

    const int tid = threadIdx.x;
    const int lane = tid & 63;
    const int w = tid >> 6;
    const int wcol = w * 128;
    const int lc = lane & 15;
    const int grp = lane >> 4;
    const int lk = grp * 8;
    const int r0 = blockIdx.x * 64;

    // per-wave B base: col = wcol + ct*16 + lc, k-slice lk..lk+7
    const __bf16* Bb1 = W2t + (size_t)(wcol + lc) * DD + lk;
    const __bf16* Bb2 = W3t + (size_t)(wcol + lc) * DD + lk;

    // ---- hoist GEMM1 kt=0 B-fragments (independent of LDS staging)
    bf16x8 bb[2][8];
    #pragma unroll
    for (int ct = 0; ct < 8; ++ct)
        bb[0][ct] = *(const bf16x8*)(Bb1 + (size_t)ct * 16 * DD);

    // ---- stage x (fp32 -> bf16, XOR-swizzled rows; non-temporal reads)
    {
        const f32x4* xv = (const f32x4*)(x + (size_t)r0 * DD);
        #pragma unroll
        for (int it = 0; it < 32; ++it) {
            const int idx4 = it * 256 + tid;
            const int row = idx4 >> 7;      // 128 float4 per row
            const int c4 = idx4 & 127;
            const f32x4 v = __builtin_nontemporal_load(xv + (size_t)row * 128 + c4);
            uint2 u;
            u.x = (unsigned)bfbits(v[0]) | ((unsigned)bfbits(v[1]) << 16);
            u.y = (unsigned)bfbits(v[2]) | ((unsigned)bfbits(v[3]) << 16);
            const int off = row * 1024 + ((c4 * 8) ^ ((row & 7) << 4));
            *(uint2*)((char*)lds_s + off) = u;
        }
    }
    __syncthreads();

    float b2v[8], bov[8];
    #pragma unroll
    for (int ct = 0; ct < 8; ++ct) {
        b2v[ct] = b2[wcol + ct * 16 + lc];
        bov[ct] = bo[wcol + ct * 16 + lc];
    }

    // A-fragment LDS read (swizzled). row fixed per rt; k0 varies.
    #define LDA(rt, k0) \
        (*(const bf16x8*)((const char*)lds_s + \
            ((rt) * 16 + lc) * 1024 + ((((k0) + lk) * 2) ^ ((((rt) * 16 + lc) & 7) << 4))))

    // ---- GEMM1: S = x @ W2 (K=512), pipelined
    f32x4 acc[4][8];
    #pragma unroll
    for (int rt = 0; rt < 4; ++rt)
        #pragma unroll
        for (int ct = 0; ct < 8; ++ct)
            acc[rt][ct] = (f32x4){0.f, 0.f, 0.f, 0.f};

    bf16x8 aa[2][4];
    #pragma unroll
    for (int rt = 0; rt < 4; ++rt) aa[0][rt] = LDA(rt, 0);

    #pragma unroll
    for (int kt = 0; kt < 16; ++kt) {
        const int cur = kt & 1, nxt = cur ^ 1;
        if (kt < 15) {
            const int k0n = (kt + 1) * 32;
            #pragma unroll
            for (int ct = 0; ct < 8; ++ct)
                bb[nxt][ct] = *(const bf16x8*)(Bb1 + (size_t)ct * 16 * DD + k0n);
            #pragma unroll
            for (int rt = 0; rt < 4; ++rt) aa[nxt][rt] = LDA(rt, k0n);
        }
        __builtin_amdgcn_s_setprio(1);
        #pragma unroll
        for (int rt = 0; rt < 4; ++rt)
            #pragma unroll
            for (int ct = 0; ct < 8; ++ct)
                acc[rt][ct] = __builtin_amdgcn_mfma_f32_16x16x32_bf16(aa[cur][rt], bb[cur][ct], acc[rt][ct], 0, 0, 0);
        __builtin_amdgcn_s_setprio(0);
    }

    // ---- hoist GEMM2 kt=0 B-fragments (hide their latency under softmax)
    bf16x8 bb2[2][8];
    #pragma unroll
    for (int ct = 0; ct < 8; ++ct)
        bb2[0][ct] = *(const bf16x8*)(Bb2 + (size_t)ct * 16 * DD);

    __syncthreads();   // everyone done reading x from LDS

    // ---- softmax per head (64-col chunks), write attn (bf16) back to LDS
    #pragma unroll
    for (int rt = 0; rt < 4; ++rt) {
        const int rloc0 = rt * 16 + grp * 4;
        const int4 mv = *(const int4*)(mask + r0 + rloc0);
        const int mk[4] = {mv.x, mv.y, mv.z, mv.w};
        #pragma unroll
        for (int hl = 0; hl < 2; ++hl) {
            #pragma unroll
            for (int j = 0; j < 4; ++j) {
                float s0 = (acc[rt][hl * 4 + 0][j] + b2v[hl * 4 + 0]) * 0.125f;
                float s1 = (acc[rt][hl * 4 + 1][j] + b2v[hl * 4 + 1]) * 0.125f;
                float s2 = (acc[rt][hl * 4 + 2][j] + b2v[hl * 4 + 2]) * 0.125f;
                float s3 = (acc[rt][hl * 4 + 3][j] + b2v[hl * 4 + 3]) * 0.125f;
                float mx = fmaxf(fmaxf(s0, s1), fmaxf(s2, s3));
                mx = fmaxf(mx, __shfl_xor(mx, 1));
                mx = fmaxf(mx, __shfl_xor(mx, 2));
                mx = fmaxf(mx, __shfl_xor(mx, 4));
                mx = fmaxf(mx, __shfl_xor(mx, 8));
                float p0 = __expf(s0 - mx);
                float p1 = __expf(s1 - mx);
                float p2 = __expf(s2 - mx);
                float p3 = __expf(s3 - mx);
                float sm = (p0 + p1) + (p2 + p3);
                sm += __shfl_xor(sm, 1);
                sm += __shfl_xor(sm, 2);
                sm += __shfl_xor(sm, 4);
                sm += __shfl_xor(sm, 8);
                float a0, a1, a2, a3;
                if (mk[j] == 0) {
                    a0 = a1 = a2 = a3 = 0.015625f;   // fp32 -1e9 bias rounds to uniform attn
                } else {
                    const float inv = 1.0f / sm;
                    a0 = p0 * inv; a1 = p1 * inv; a2 = p2 * inv; a3 = p3 * inv;
                }
                const int row = rloc0 + j;
                const int base = row * 1024;
                const int sw = (row & 7) << 4;
                *(short*)((char*)lds_s + base + (((wcol + (hl * 4 + 0) * 16 + lc) * 2) ^ sw)) = (short)bfbits(a0);
                *(short*)((char*)lds_s + base + (((wcol + (hl * 4 + 1) * 16 + lc) * 2) ^ sw)) = (short)bfbits(a1);
                *(short*)((char*)lds_s + base + (((wcol + (hl * 4 + 2) * 16 + lc) * 2) ^ sw)) = (short)bfbits(a2);
                *(short*)((char*)lds_s + base + (((wcol + (hl * 4 + 3) * 16 + lc) * 2) ^ sw)) = (short)bfbits(a3);
            }
        }
    }
    __syncthreads();   // attn tile complete in LDS

    // ---- GEMM2: out = attn @ W3 (K=512) + bo, pipelined
    f32x4 acc2[4][8];
    #pragma unroll
    for (int rt = 0; rt < 4; ++rt)
        #pragma unroll
        for (int ct = 0; ct < 8; ++ct)
            acc2[rt][ct] = (f32x4){0.f, 0.f, 0.f, 0.f};

    bf16x8 aa2[2][4];
    #pragma unroll
    for (int rt = 0; rt < 4; ++rt) aa2[0][rt] = LDA(rt, 0);

    #pragma unroll
    for (int kt = 0; kt < 16; ++kt) {
        const int cur = kt & 1, nxt = cur ^ 1;
        if (kt < 15) {
            const int k0n = (kt + 1) * 32;
            #pragma unroll
            for (int ct = 0; ct < 8; ++ct)
                bb2[nxt][ct] = *(const bf16x8*)(Bb2 + (size_t)ct * 16 * DD + k0n);
            #pragma unroll
            for (int rt = 0; rt < 4; ++rt) aa2[nxt][rt] = LDA(rt, k0n);
        }
        __builtin_amdgcn_s_setprio(1);
        #pragma unroll
        for (int rt = 0; rt < 4; ++rt)
            #pragma unroll
            for (int ct = 0; ct < 8; ++ct)
                acc2[rt][ct] = __builtin_amdgcn_mfma_f32_16x16x32_bf16(aa2[cur][rt], bb2[cur][ct], acc2[rt][ct], 0, 0, 0);
        __builtin_amdgcn_s_setprio(0);
    }
    #undef LDA

    // ---- epilogue: + bo, non-temporal fp32 store, row-major so the eight
    // 64B segments per row are adjacent in program order (write-combine).
    #pragma unroll
    for (int rt = 0; rt < 4; ++rt) {
        #pragma unroll
        for (int j = 0; j < 4; ++j) {
            const int gr = r0 + rt * 16 + grp * 4 + j;
            float* orow = out + (size_t)gr * DD + wcol + lc;
            #pragma unroll
            for (int ct = 0; ct < 8; ++ct)
                __builtin_nontemporal_store(acc2[rt][ct][j] + bov[ct], orow + ct * 16);
        }
    }
}

extern "C" void kernel_launch(void* const* d_in, const int* in_sizes, int n_in,
                              void* d_out, int out_size, void* d_ws, size_t ws_size,
                              hipStream_t stream) {
    const float* qf     = (const float*)d_in[0];
    const int*   mask   = (const int*)d_in[1];
    const float* memory = (const float*)d_in[2];
    const float* Wq     = (const float*)d_in[3];
    const float* bq     = (const float*)d_in[4];
    const float* Wk     = (const float*)d_in[5];
    const float* bk     = (const float*)d_in[6];
    const float* Wv     = (const float*)d_in[7];
    const float* bv     = (const float*)d_in[8];
    const float* Wo     = (const float*)d_in[9];
    const float* bo     = (const float*)d_in[10];

    char* ws = (char*)d_ws;
    float*  kproj = (float*)ws;                  // 128 KB
    float*  vproj = (float*)(ws + 131072);       // 128 KB
    float*  b2    = (float*)(ws + 262144);       // 2 KB
    __bf16* W2t   = (__bf16*)(ws + 264192);      // 512 KB
    __bf16* W3t   = (__bf16*)(ws + 788480);      // 512 KB

    prep_kv<<<64, 256, 0, stream>>>(memory, Wk, bk, Wv, bv, kproj, vproj);
    prep_w<<<512, 256, 0, stream>>>(Wq, bq, Wo, kproj, vproj, W2t, b2, W3t);
    attn_main<<<2048, 256, 0, stream>>>(qf, mask, W2t, b2, W3t, bo, (float*)d_out);
}